// Round 7
// baseline (707.990 us; speedup 1.0000x reference)
//
#include <hip/hip_runtime.h>

#define T_ 3
#define B_ 4
#define N_ 4096
#define K_ 8

// Uniform 7-resident grid: 256 groups of 7 = {4 KNN, 3 chamfer}.
// 256%7 != 0 -> every CU gets all 7 role-slots exactly once (bijective mix).
#define GRP_SZ  7
#define GRP_KNN 4
#define GROUPS  256
#define CWIN 512    // candidate window (16 KiB pre-packed A-frags)

// Workspace: 20 candidate-sets x 8 windows x 1024 uint4 (16 KiB/window).
//   sets 0..3   = KNN src[b]        (16x16x32 layout)
//   sets 4..15  = CH  dp[t*B+b]     (32x32x16 layout)
//   sets 16..19 = CH  tp[b]         (32x32x16 layout)
#define SET_U4 8192          // uint4s per set
#define WS_U4  (20 * SET_U4) // 163840 uint4 = 2.62 MB

typedef short bf16x8 __attribute__((ext_vector_type(8)));
typedef float f32x4  __attribute__((ext_vector_type(4)));
typedef float f32x16 __attribute__((ext_vector_type(16)));

// ---------------------------------------------------------------------------
template <int NW>
__device__ inline float block_reduce(float v, float* scratch) {
    #pragma unroll
    for (int off = 32; off > 0; off >>= 1) v += __shfl_down(v, off, 64);
    const int lane = threadIdx.x & 63, wid = threadIdx.x >> 6;
    if (lane == 0) scratch[wid] = v;
    __syncthreads();
    float s = 0.f;
    if (threadIdx.x == 0) {
        #pragma unroll
        for (int w = 0; w < NW; ++w) s += scratch[w];
    }
    return s;  // valid on thread 0 only
}

// Batcher odd-even 8-sort (19 CEs) — independent of running list (ILP).
#define CE_(A, i, j) { unsigned lo_ = min(A[i], A[j]); A[j] = max(A[i], A[j]); A[i] = lo_; }
__device__ inline void sort8(unsigned s[8]) {
    CE_(s,0,1) CE_(s,2,3) CE_(s,4,5) CE_(s,6,7)
    CE_(s,0,2) CE_(s,1,3) CE_(s,4,6) CE_(s,5,7)
    CE_(s,1,2) CE_(s,5,6)
    CE_(s,0,4) CE_(s,1,5) CE_(s,2,6) CE_(s,3,7)
    CE_(s,2,4) CE_(s,3,5)
    CE_(s,1,2) CE_(s,3,4) CE_(s,5,6)
}
// a (asc) := lowest-8 of union(a asc, s asc), sorted. Half-clean + bitonic merge.
__device__ inline void merge_top8(unsigned a[8], const unsigned s[8]) {
    #pragma unroll
    for (int i = 0; i < 8; ++i) a[i] = min(a[i], s[7 - i]);  // bitonic, lowest 8
    CE_(a,0,4) CE_(a,1,5) CE_(a,2,6) CE_(a,3,7)
    CE_(a,0,2) CE_(a,1,3) CE_(a,4,6) CE_(a,5,7)
    CE_(a,0,1) CE_(a,2,3) CE_(a,4,5) CE_(a,6,7)
}

// bf16 hi/lo split helpers (truncation; residual captures 8 more mantissa bits)
__device__ inline short hi16(float v) { return (short)(__float_as_uint(v) >> 16); }
__device__ inline float residual(float v) {
    return v - __uint_as_float(__float_as_uint(v) & 0xFFFF0000u);
}
__device__ inline unsigned pk2(short a, short b) {
    return (unsigned)(unsigned short)a | ((unsigned)(unsigned short)b << 16);
}
#define BF16_ONE ((short)0x3F80)

// Stage one 16 KiB pre-packed window into alds: 4 async 16B global->LDS copies
// per wave (fire-and-forget, vmcnt-counted; compiler's vmcnt(0) drain at the
// next s_barrier is the synchronization). LDS base wave-uniform (m104);
// hardware adds lane*16. Zero VGPR round-trip, zero staging VALU.
__device__ inline void stage_async(const uint4* pk, int W, uint4* alds,
                                   int wid, int lane) {
    #pragma unroll
    for (int c = 0; c < 4; ++c) {
        const int chunk = wid * 4 + c;  // 16 chunks of 1 KiB
        __builtin_amdgcn_global_load_lds(
            (const __attribute__((address_space(1))) void*)(pk + W * 1024 + chunk * 64 + lane),
            (__attribute__((address_space(3))) void*)(alds + chunk * 64),
            16, 0, 0);
    }
}

// ---------------------------------------------------------------------------
// Prep: pack A-frags once per candidate point (vs 32-256x re-pack per block).
// Math is bit-identical to the verified in-kernel staging expressions.
__global__ __launch_bounds__(256) void prep_kernel(const float* __restrict__ src,
                                                   const float* __restrict__ dp_all,
                                                   const float* __restrict__ tp,
                                                   uint4* __restrict__ ws) {
    const int gid = blockIdx.x * 256 + threadIdx.x;  // 0..81919
    const int set = gid >> 12, j = gid & (N_ - 1);
    const float* base;
    if (set < 4)       base = src    + (size_t)set * N_ * 3;
    else if (set < 16) base = dp_all + (size_t)(set - 4) * N_ * 3;
    else               base = tp     + (size_t)(set - 16) * N_ * 3;

    float x = base[3 * j], y = base[3 * j + 1], z = base[3 * j + 2];
    float p2 = fmaf(x, x, fmaf(y, y, z * z));
    float mx = -2.f * x, my = -2.f * y, mz = -2.f * z;
    short mhx = hi16(mx), mhy = hi16(my), mhz = hi16(mz);
    short mlx = hi16(residual(mx)), mly = hi16(residual(my)), mlz = hi16(residual(mz));
    unsigned w0 = pk2(mhx, mhy), w1 = pk2(mhz, mlx), w2 = pk2(mly, mlz);
    unsigned pw2 = pk2(hi16(p2), hi16(residual(p2)));

    const int w = j >> 9, jloc = j & (CWIN - 1);
    if (set < 4) {  // KNN 16x16x32 layout: [tile*32 + m] / +16
        const int tile = jloc >> 4, m = jloc & 15;
        uint4* o = ws + (size_t)set * SET_U4 + w * 1024 + tile * 32 + m;
        o[0]  = make_uint4(w0, w1, w2, pw2);                      // k0-7
        o[16] = make_uint4(w0, w1, w2, pk2(BF16_ONE, BF16_ONE));  // k8-15
    } else {        // CH 32x32x16 layout: [jloc] / [512+jloc]
        uint4* o = ws + (size_t)set * SET_U4 + w * 1024 + jloc;
        o[0]   = make_uint4(w0, w1, w2, w0);                       // k0-7
        o[512] = make_uint4(w1, w2, pw2, pk2(BF16_ONE, BF16_ONE)); // k8-15
    }
}

// ---------------------------------------------------------------------------
__global__ __launch_bounds__(256, 7) void mega_kernel(const float* __restrict__ src,
                                                      const float* __restrict__ dp_all,
                                                      const float* __restrict__ tp,
                                                      const float* __restrict__ drp,
                                                      const float* __restrict__ pw,
                                                      const float* __restrict__ rm,
                                                      const uint4* __restrict__ ws,
                                                      float* __restrict__ out) {
    __shared__ uint4 smem4[1024];  // 16 KiB frag buffer, shared by all roles
    const f32x4 zero4 = {0.f, 0.f, 0.f, 0.f};
    uint4* alds = smem4;

    const int g = blockIdx.x / GRP_SZ;
    const int r = blockIdx.x % GRP_SZ;
    const int lane = threadIdx.x & 63;
    const int wid  = __builtin_amdgcn_readfirstlane(threadIdx.x >> 6);

    if (r < GRP_KNN) {  // ================= KNN + ARAP role (verified body)
        const int knn_id = g * GRP_KNN + r;  // 0..1023
        const int b   = knn_id / (N_ / 16);
        const int qt0 = (knn_id % (N_ / 16)) * 16;  // 16 queries/block
        const float* sb = src + (size_t)b * N_ * 3;
        const uint4* pk = ws + (size_t)b * SET_U4;

        const int n    = lane & 15;   // query col
        const int quad = lane >> 4;
        const int rbase = quad * 4;   // D-row base (candidate offset in tile)
        const int qid  = qt0 + n;

        // B-frag: this lane's query, hi/lo split; |q|^2 injected at k14/k15.
        bf16x8 bfrag = (bf16x8)(short)0;
        {
            float x = sb[3 * qid], y = sb[3 * qid + 1], z = sb[3 * qid + 2];
            float q2 = fmaf(x, x, fmaf(y, y, z * z));
            short hx = hi16(x), hy = hi16(y), hz = hi16(z);
            short lx = hi16(residual(x)), ly = hi16(residual(y)), lz = hi16(residual(z));
            if (quad == 0) bfrag = (bf16x8){hx, hy, hz, hx, hy, hz, BF16_ONE, BF16_ONE};
            else if (quad == 1) bfrag = (bf16x8){lx, ly, lz, lx, ly, lz,
                                                 hi16(q2), hi16(residual(q2))};
        }

        unsigned a[K_];
        #pragma unroll
        for (int p = 0; p < K_; ++p) a[p] = 0xFFFFFFFFu;

        stage_async(pk, 0, alds, wid, lane);  // prologue: window 0

        for (int w = 0; w < N_ / CWIN; ++w) {  // 8 windows of 512 candidates
            __syncthreads();  // vmcnt(0) drain: alds = window w frags

            // This wave's quarter: tiles wid*8 .. wid*8+7 (batches of 2 tiles).
            #pragma unroll
            for (int bt = 0; bt < 4; ++bt) {
                unsigned s8[8];
                #pragma unroll
                for (int h = 0; h < 2; ++h) {
                    const int tile = wid * 8 + bt * 2 + h;
                    const int tbg  = w * CWIN + tile * 16;  // 16-aligned
                    bf16x8 af = (bf16x8)(short)0;
                    if (quad < 2) {
                        union { uint4 u; bf16x8 v; } cv;
                        cv.u = alds[tile * 32 + quad * 16 + n];
                        af = cv.v;
                    }
                    f32x4 d = __builtin_amdgcn_mfma_f32_16x16x32_bf16(af, bfrag, zero4, 0, 0, 0);
                    #pragma unroll
                    for (int rr = 0; rr < 4; ++rr)  // idx bits (0-11) disjoint from tbg
                        s8[h * 4 + rr] = (__float_as_uint(d[rr]) & 0xFFFFF000u)
                                         | (unsigned)(tbg | (rbase + rr));
                    if (tbg == qt0) {  // wave-uniform: the one self-overlap tile
                        #pragma unroll
                        for (int rr = 0; rr < 4; ++rr)
                            if (rbase + rr == n) s8[h * 4 + rr] = 0xFFFFFFFFu;
                    }
                }
                sort8(s8);
                merge_top8(a, s8);
            }

            __syncthreads();  // all waves done reading alds
            if (w + 1 < N_ / CWIN) stage_async(pk, w + 1, alds, wid, lane);
        }

        // Fold the 4 row-quads of each query column (lanes n, n+16, n+32, n+48).
        #pragma unroll
        for (int mk = 16; mk <= 32; mk <<= 1) {
            unsigned t[8];
            #pragma unroll
            for (int e = 0; e < K_; ++e) t[e] = __shfl_xor(a[e], mk, 64);
            merge_top8(a, t);
        }

        // Cross-wave merge (4 partial lists per query) + publish indices.
        __syncthreads();  // A-frag reads done; reuse LDS
        unsigned* sm = (unsigned*)smem4;          // [wave*16+q]*9+e  (<576)
        unsigned* nidx = (unsigned*)smem4 + 1024; // 128 entries
        if (lane < 16) {
            #pragma unroll
            for (int e = 0; e < K_; ++e) sm[(wid * 16 + n) * 9 + e] = a[e];
        }
        __syncthreads();
        if (threadIdx.x < 16) {
            const int q = threadIdx.x;
            unsigned md[K_];
            #pragma unroll
            for (int e = 0; e < K_; ++e) md[e] = sm[q * 9 + e];
            #pragma unroll
            for (int wv = 1; wv < 4; ++wv) {
                unsigned t[8];
                #pragma unroll
                for (int e = 0; e < K_; ++e) t[e] = sm[(wv * 16 + q) * 9 + e];
                merge_top8(md, t);
            }
            #pragma unroll
            for (int e = 0; e < K_; ++e) nidx[q * 8 + e] = md[e] & 0xFFFu;
        }
        __syncthreads();

        // Fused ARAP: 128 threads = 16 queries x 8 neighbors, all 3 t stages.
        float acc = 0.f;
        if (threadIdx.x < 16 * K_) {
            const int q  = threadIdx.x >> 3;
            const int qi = qt0 + q;
            const int j  = (int)nidx[threadIdx.x];
            float sx = sb[3 * qi], sy = sb[3 * qi + 1], sz = sb[3 * qi + 2];
            float ex = sb[3 * j] - sx, ey = sb[3 * j + 1] - sy, ez = sb[3 * j + 2] - sz;
            float sd = sqrtf(fmaf(ex, ex, fmaf(ey, ey, ez * ez)) + 1e-5f);
            #pragma unroll
            for (int t = 0; t < T_; ++t) {
                const float* dpb = dp_all + ((size_t)(t * B_ + b)) * N_ * 3;
                float dx = dpb[3 * j] - dpb[3 * qi];
                float dy = dpb[3 * j + 1] - dpb[3 * qi + 1];
                float dz = dpb[3 * j + 2] - dpb[3 * qi + 2];
                float dd = sqrtf(fmaf(dx, dx, fmaf(dy, dy, dz * dz)) + 1e-5f);
                float df = dd - sd;
                acc = fmaf(df, df, acc);
            }
        }
        float s = block_reduce<4>(acc, (float*)smem4);
        if (threadIdx.x == 0) atomicAdd(out, s * (1.0f / B_));

    } else {  // ====== chamfer role — 32x32x16 (verified body, 128 q/block)
        const f32x16 zero16 = {0.f,0.f,0.f,0.f, 0.f,0.f,0.f,0.f,
                               0.f,0.f,0.f,0.f, 0.f,0.f,0.f,0.f};
        const int cid   = g * 3 + (r - GRP_KNN);  // 0..767
        const int combo = cid >> 5;   // ((t*B+b)*2+dir), 0..23
        const int slab  = cid & 31;   // 128-query slab
        const int dir = combo & 1;
        const int tb  = combo >> 1;
        const int b = tb % B_, t = tb / B_;

        const float* dpb = dp_all + ((size_t)(t * B_ + b)) * N_ * 3;
        const float* tpb = tp + (size_t)b * N_ * 3;
        const float* qbase = dir ? tpb : dpb;  // queries
        // candidates = dir ? dp[tb] : tp[b] -> pre-packed set id:
        const int cset = dir ? (4 + tb) : (16 + b);
        const uint4* pkc = ws + (size_t)cset * SET_U4;

        const int col = lane & 31;   // query column (B) / A-row within tile
        const int kg  = lane >> 5;   // k-octet (0: k0-7, 1: k8-15)

        bf16x8 bfrag;
        {
            const int qid = slab * 128 + wid * 32 + col;
            float x = qbase[3 * qid], y = qbase[3 * qid + 1], z = qbase[3 * qid + 2];
            float q2 = fmaf(x, x, fmaf(y, y, z * z));
            short hx = hi16(x), hy = hi16(y), hz = hi16(z);
            short lx = hi16(residual(x)), ly = hi16(residual(y)), lz = hi16(residual(z));
            if (kg == 0) bfrag = (bf16x8){hx, hy, hz, hx, hy, hz, lx, ly};
            else bfrag = (bf16x8){lz, lx, ly, lz, BF16_ONE, BF16_ONE,
                                  hi16(q2), hi16(residual(q2))};
        }

        float run = 3.4e38f;

        stage_async(pkc, 0, alds, wid, lane);  // prologue: window 0

        for (int w = 0; w < N_ / CWIN; ++w) {
            __syncthreads();  // vmcnt(0) drain: alds = window w frags

            #pragma unroll
            for (int tile = 0; tile < CWIN / 32; ++tile) {
                union { uint4 u; bf16x8 v; } cv;
                cv.u = alds[kg * 512 + tile * 32 + col];
                f32x16 d = __builtin_amdgcn_mfma_f32_32x32x16_bf16(cv.v, bfrag, zero16, 0, 0, 0);
                float m0 = fminf(fminf(d[0],  d[1]),  fminf(d[2],  d[3]));
                float m1 = fminf(fminf(d[4],  d[5]),  fminf(d[6],  d[7]));
                float m2 = fminf(fminf(d[8],  d[9]),  fminf(d[10], d[11]));
                float m3 = fminf(fminf(d[12], d[13]), fminf(d[14], d[15]));
                run = fminf(run, fminf(fminf(m0, m1), fminf(m2, m3)));
            }

            __syncthreads();  // all waves done reading alds
            if (w + 1 < N_ / CWIN) stage_async(pkc, w + 1, alds, wid, lane);
        }

        // lane and lane+32 hold disjoint candidate rows of the same query col.
        run = fminf(run, __shfl_xor(run, 32, 64));
        float contrib = (lane < 32) ? run * (0.5f / B_) : 0.f;  // q2 inside MFMA

        // pd + sp + tran folded here (768 blocks x 256 thr >= all elem counts).
        {
            const int PD_N = T_ * B_ * N_ * 3;
            const int SP_N = T_ * B_ * N_;
            const int gid = cid * 256 + (int)threadIdx.x;  // 0..196607
            if (gid < PD_N) {
                float d2 = drp[gid] - dp_all[gid];
                contrib = fmaf(d2 * (1.0f / B_), d2, contrib);
            }
            if (gid < SP_N) contrib += fabsf(pw[gid]) * (1.0f / (B_ * N_));
            if (gid < T_ * B_ * 3) {
                int tt = gid / (B_ * 3);
                int b2 = (gid / 3) % B_;
                int rr = gid % 3;
                float v = rm[tt * B_ * 16 + b2 * 16 + rr * 4 + 3];
                contrib = fmaf(v * (1.0f / B_), v, contrib);
            }
        }
        __syncthreads();
        float ssum = block_reduce<4>(contrib, (float*)smem4);
        if (threadIdx.x == 0) atomicAdd(out, ssum);
    }
}

// ---------------------------------------------------------------------------
extern "C" void kernel_launch(void* const* d_in, const int* in_sizes, int n_in,
                              void* d_out, int out_size, void* d_ws, size_t ws_size,
                              hipStream_t stream) {
    const float* pw  = (const float*)d_in[1];
    const float* drp = (const float*)d_in[2];
    const float* dp  = (const float*)d_in[3];
    const float* rm  = (const float*)d_in[4];
    const float* sp  = (const float*)d_in[5];
    const float* tp  = (const float*)d_in[6];
    float* out = (float*)d_out;
    uint4* ws = (uint4*)d_ws;  // needs 2.62 MB

    hipMemsetAsync(out, 0, sizeof(float), stream);
    prep_kernel<<<(20 * N_) / 256, 256, 0, stream>>>(sp, dp, tp, ws);
    mega_kernel<<<GROUPS * GRP_SZ, 256, 0, stream>>>(sp, dp, tp, drp, pw, rm, ws, out);
}

// Round 8
// 120.535 us; speedup vs baseline: 5.8738x; 5.8738x over previous
//
#include <hip/hip_runtime.h>

#define T_ 3
#define B_ 4
#define N_ 4096
#define K_ 8

// Uniform 7-resident grid: 256 groups of 7 = {4 KNN, 3 chamfer}.
#define GRP_SZ  7
#define GRP_KNN 4
#define GROUPS  256
#define CWIN 512    // candidate window (16 KiB pre-packed A-frags)

// Workspace: 20 candidate-sets x 8 windows x 1024 uint4 (16 KiB/window),
// each window stored as the EXACT alds image (verified by r7's refcheck).
//   sets 0..3   = KNN src[b]        (16x16x32 layout)
//   sets 4..15  = CH  dp[t*B+b]     (32x32x16 layout)
//   sets 16..19 = CH  tp[b]         (32x32x16 layout)
#define SET_U4 8192          // uint4s per set
#define WS_U4  (20 * SET_U4) // 163840 uint4 = 2.62 MB

typedef short bf16x8 __attribute__((ext_vector_type(8)));
typedef float f32x4  __attribute__((ext_vector_type(4)));
typedef float f32x16 __attribute__((ext_vector_type(16)));

// ---------------------------------------------------------------------------
template <int NW>
__device__ inline float block_reduce(float v, float* scratch) {
    #pragma unroll
    for (int off = 32; off > 0; off >>= 1) v += __shfl_down(v, off, 64);
    const int lane = threadIdx.x & 63, wid = threadIdx.x >> 6;
    if (lane == 0) scratch[wid] = v;
    __syncthreads();
    float s = 0.f;
    if (threadIdx.x == 0) {
        #pragma unroll
        for (int w = 0; w < NW; ++w) s += scratch[w];
    }
    return s;  // valid on thread 0 only
}

// Batcher odd-even 8-sort (19 CEs) — independent of running list (ILP).
#define CE_(A, i, j) { unsigned lo_ = min(A[i], A[j]); A[j] = max(A[i], A[j]); A[i] = lo_; }
__device__ inline void sort8(unsigned s[8]) {
    CE_(s,0,1) CE_(s,2,3) CE_(s,4,5) CE_(s,6,7)
    CE_(s,0,2) CE_(s,1,3) CE_(s,4,6) CE_(s,5,7)
    CE_(s,1,2) CE_(s,5,6)
    CE_(s,0,4) CE_(s,1,5) CE_(s,2,6) CE_(s,3,7)
    CE_(s,2,4) CE_(s,3,5)
    CE_(s,1,2) CE_(s,3,4) CE_(s,5,6)
}
// a (asc) := lowest-8 of union(a asc, s asc), sorted. Half-clean + bitonic merge.
__device__ inline void merge_top8(unsigned a[8], const unsigned s[8]) {
    #pragma unroll
    for (int i = 0; i < 8; ++i) a[i] = min(a[i], s[7 - i]);  // bitonic, lowest 8
    CE_(a,0,4) CE_(a,1,5) CE_(a,2,6) CE_(a,3,7)
    CE_(a,0,2) CE_(a,1,3) CE_(a,4,6) CE_(a,5,7)
    CE_(a,0,1) CE_(a,2,3) CE_(a,4,5) CE_(a,6,7)
}

// bf16 hi/lo split helpers (truncation; residual captures 8 more mantissa bits)
__device__ inline short hi16(float v) { return (short)(__float_as_uint(v) >> 16); }
__device__ inline float residual(float v) {
    return v - __uint_as_float(__float_as_uint(v) & 0xFFFF0000u);
}
__device__ inline unsigned pk2(short a, short b) {
    return (unsigned)(unsigned short)a | ((unsigned)(unsigned short)b << 16);
}
#define BF16_ONE ((short)0x3F80)

// ---------------------------------------------------------------------------
// Prep: pack A-frags once per candidate point (vs 32-256x re-pack per block).
// Math is bit-identical to the verified in-kernel staging expressions; output
// layout is the verbatim 16 KiB alds image per window. (Refcheck'd in r7.)
__global__ __launch_bounds__(256) void prep_kernel(const float* __restrict__ src,
                                                   const float* __restrict__ dp_all,
                                                   const float* __restrict__ tp,
                                                   uint4* __restrict__ ws) {
    const int gid = blockIdx.x * 256 + threadIdx.x;  // 0..81919
    const int set = gid >> 12, j = gid & (N_ - 1);
    const float* base;
    if (set < 4)       base = src    + (size_t)set * N_ * 3;
    else if (set < 16) base = dp_all + (size_t)(set - 4) * N_ * 3;
    else               base = tp     + (size_t)(set - 16) * N_ * 3;

    float x = base[3 * j], y = base[3 * j + 1], z = base[3 * j + 2];
    float p2 = fmaf(x, x, fmaf(y, y, z * z));
    float mx = -2.f * x, my = -2.f * y, mz = -2.f * z;
    short mhx = hi16(mx), mhy = hi16(my), mhz = hi16(mz);
    short mlx = hi16(residual(mx)), mly = hi16(residual(my)), mlz = hi16(residual(mz));
    unsigned w0 = pk2(mhx, mhy), w1 = pk2(mhz, mlx), w2 = pk2(mly, mlz);
    unsigned pw2 = pk2(hi16(p2), hi16(residual(p2)));

    const int w = j >> 9, jloc = j & (CWIN - 1);
    if (set < 4) {  // KNN 16x16x32 layout: [tile*32 + m] / +16
        const int tile = jloc >> 4, m = jloc & 15;
        uint4* o = ws + (size_t)set * SET_U4 + w * 1024 + tile * 32 + m;
        o[0]  = make_uint4(w0, w1, w2, pw2);                      // k0-7
        o[16] = make_uint4(w0, w1, w2, pk2(BF16_ONE, BF16_ONE));  // k8-15
    } else {        // CH 32x32x16 layout: [jloc] / [512+jloc]
        uint4* o = ws + (size_t)set * SET_U4 + w * 1024 + jloc;
        o[0]   = make_uint4(w0, w1, w2, w0);                       // k0-7
        o[512] = make_uint4(w1, w2, pw2, pk2(BF16_ONE, BF16_ONE)); // k8-15
    }
}

// ---------------------------------------------------------------------------
__global__ __launch_bounds__(256, 7) void mega_kernel(const float* __restrict__ src,
                                                      const float* __restrict__ dp_all,
                                                      const float* __restrict__ tp,
                                                      const float* __restrict__ drp,
                                                      const float* __restrict__ pw,
                                                      const float* __restrict__ rm,
                                                      const uint4* __restrict__ ws,
                                                      float* __restrict__ out) {
    __shared__ uint4 smem4[1024];  // 16 KiB frag buffer, shared by all roles
    const f32x4 zero4 = {0.f, 0.f, 0.f, 0.f};
    uint4* alds = smem4;

    const int g = blockIdx.x / GRP_SZ;
    const int r = blockIdx.x % GRP_SZ;
    const int lane = threadIdx.x & 63;
    const int wid  = __builtin_amdgcn_readfirstlane(threadIdx.x >> 6);

    if (r < GRP_KNN) {  // ================= KNN + ARAP role (verified body)
        const int knn_id = g * GRP_KNN + r;  // 0..1023
        const int b   = knn_id / (N_ / 16);
        const int qt0 = (knn_id % (N_ / 16)) * 16;  // 16 queries/block
        const float* sb = src + (size_t)b * N_ * 3;
        const uint4* pk = ws + (size_t)b * SET_U4;

        const int n    = lane & 15;   // query col
        const int quad = lane >> 4;
        const int rbase = quad * 4;   // D-row base (candidate offset in tile)
        const int qid  = qt0 + n;

        // B-frag: this lane's query, hi/lo split; |q|^2 injected at k14/k15.
        bf16x8 bfrag = (bf16x8)(short)0;
        {
            float x = sb[3 * qid], y = sb[3 * qid + 1], z = sb[3 * qid + 2];
            float q2 = fmaf(x, x, fmaf(y, y, z * z));
            short hx = hi16(x), hy = hi16(y), hz = hi16(z);
            short lx = hi16(residual(x)), ly = hi16(residual(y)), lz = hi16(residual(z));
            if (quad == 0) bfrag = (bf16x8){hx, hy, hz, hx, hy, hz, BF16_ONE, BF16_ONE};
            else if (quad == 1) bfrag = (bf16x8){lx, ly, lz, lx, ly, lz,
                                                 hi16(q2), hi16(residual(q2))};
        }

        unsigned a[K_];
        #pragma unroll
        for (int p = 0; p < K_; ++p) a[p] = 0xFFFFFFFFu;

        for (int w = 0; w < N_ / CWIN; ++w) {  // 8 windows of 512 candidates
            __syncthreads();  // previous window's alds reads done
            // Stage: verbatim copy of the pre-packed 16 KiB window image.
            // 4 x (global_load_dwordx4 from L2-resident ws -> ds_write_b128);
            // zero packing VALU, nothing live across barriers.
            {
                const uint4* pkw = pk + w * 1024;
                #pragma unroll
                for (int c = 0; c < 4; ++c) {
                    const int i = c * 256 + (int)threadIdx.x;
                    alds[i] = pkw[i];
                }
            }
            __syncthreads();

            // This wave's quarter: tiles wid*8 .. wid*8+7 (batches of 2 tiles).
            #pragma unroll
            for (int bt = 0; bt < 4; ++bt) {
                unsigned s8[8];
                #pragma unroll
                for (int h = 0; h < 2; ++h) {
                    const int tile = wid * 8 + bt * 2 + h;
                    const int tbg  = w * CWIN + tile * 16;  // 16-aligned
                    bf16x8 af = (bf16x8)(short)0;
                    if (quad < 2) {
                        union { uint4 u; bf16x8 v; } cv;
                        cv.u = alds[tile * 32 + quad * 16 + n];
                        af = cv.v;
                    }
                    f32x4 d = __builtin_amdgcn_mfma_f32_16x16x32_bf16(af, bfrag, zero4, 0, 0, 0);
                    #pragma unroll
                    for (int rr = 0; rr < 4; ++rr)  // idx bits (0-11) disjoint from tbg
                        s8[h * 4 + rr] = (__float_as_uint(d[rr]) & 0xFFFFF000u)
                                         | (unsigned)(tbg | (rbase + rr));
                    if (tbg == qt0) {  // wave-uniform: the one self-overlap tile
                        #pragma unroll
                        for (int rr = 0; rr < 4; ++rr)
                            if (rbase + rr == n) s8[h * 4 + rr] = 0xFFFFFFFFu;
                    }
                }
                sort8(s8);
                merge_top8(a, s8);
            }
        }

        // Fold the 4 row-quads of each query column (lanes n, n+16, n+32, n+48).
        #pragma unroll
        for (int mk = 16; mk <= 32; mk <<= 1) {
            unsigned t[8];
            #pragma unroll
            for (int e = 0; e < K_; ++e) t[e] = __shfl_xor(a[e], mk, 64);
            merge_top8(a, t);
        }

        // Cross-wave merge (4 partial lists per query) + publish indices.
        __syncthreads();  // A-frag reads done; reuse LDS
        unsigned* sm = (unsigned*)smem4;          // [wave*16+q]*9+e  (<576)
        unsigned* nidx = (unsigned*)smem4 + 1024; // 128 entries
        if (lane < 16) {
            #pragma unroll
            for (int e = 0; e < K_; ++e) sm[(wid * 16 + n) * 9 + e] = a[e];
        }
        __syncthreads();
        if (threadIdx.x < 16) {
            const int q = threadIdx.x;
            unsigned md[K_];
            #pragma unroll
            for (int e = 0; e < K_; ++e) md[e] = sm[q * 9 + e];
            #pragma unroll
            for (int wv = 1; wv < 4; ++wv) {
                unsigned t[8];
                #pragma unroll
                for (int e = 0; e < K_; ++e) t[e] = sm[(wv * 16 + q) * 9 + e];
                merge_top8(md, t);
            }
            #pragma unroll
            for (int e = 0; e < K_; ++e) nidx[q * 8 + e] = md[e] & 0xFFFu;
        }
        __syncthreads();

        // Fused ARAP: 128 threads = 16 queries x 8 neighbors, all 3 t stages.
        float acc = 0.f;
        if (threadIdx.x < 16 * K_) {
            const int q  = threadIdx.x >> 3;
            const int qi = qt0 + q;
            const int j  = (int)nidx[threadIdx.x];
            float sx = sb[3 * qi], sy = sb[3 * qi + 1], sz = sb[3 * qi + 2];
            float ex = sb[3 * j] - sx, ey = sb[3 * j + 1] - sy, ez = sb[3 * j + 2] - sz;
            float sd = sqrtf(fmaf(ex, ex, fmaf(ey, ey, ez * ez)) + 1e-5f);
            #pragma unroll
            for (int t = 0; t < T_; ++t) {
                const float* dpb = dp_all + ((size_t)(t * B_ + b)) * N_ * 3;
                float dx = dpb[3 * j] - dpb[3 * qi];
                float dy = dpb[3 * j + 1] - dpb[3 * qi + 1];
                float dz = dpb[3 * j + 2] - dpb[3 * qi + 2];
                float dd = sqrtf(fmaf(dx, dx, fmaf(dy, dy, dz * dz)) + 1e-5f);
                float df = dd - sd;
                acc = fmaf(df, df, acc);
            }
        }
        float s = block_reduce<4>(acc, (float*)smem4);
        if (threadIdx.x == 0) atomicAdd(out, s * (1.0f / B_));

    } else {  // ====== chamfer role — 32x32x16 (verified body, 128 q/block)
        const f32x16 zero16 = {0.f,0.f,0.f,0.f, 0.f,0.f,0.f,0.f,
                               0.f,0.f,0.f,0.f, 0.f,0.f,0.f,0.f};
        const int cid   = g * 3 + (r - GRP_KNN);  // 0..767
        const int combo = cid >> 5;   // ((t*B+b)*2+dir), 0..23
        const int slab  = cid & 31;   // 128-query slab
        const int dir = combo & 1;
        const int tb  = combo >> 1;
        const int b = tb % B_, t = tb / B_;

        const float* dpb = dp_all + ((size_t)(t * B_ + b)) * N_ * 3;
        const float* tpb = tp + (size_t)b * N_ * 3;
        const float* qbase = dir ? tpb : dpb;  // queries
        // candidates = dir ? dp[tb] : tp[b] -> pre-packed set id:
        const int cset = dir ? (4 + tb) : (16 + b);
        const uint4* pkc = ws + (size_t)cset * SET_U4;

        const int col = lane & 31;   // query column (B) / A-row within tile
        const int kg  = lane >> 5;   // k-octet (0: k0-7, 1: k8-15)

        bf16x8 bfrag;
        {
            const int qid = slab * 128 + wid * 32 + col;
            float x = qbase[3 * qid], y = qbase[3 * qid + 1], z = qbase[3 * qid + 2];
            float q2 = fmaf(x, x, fmaf(y, y, z * z));
            short hx = hi16(x), hy = hi16(y), hz = hi16(z);
            short lx = hi16(residual(x)), ly = hi16(residual(y)), lz = hi16(residual(z));
            if (kg == 0) bfrag = (bf16x8){hx, hy, hz, hx, hy, hz, lx, ly};
            else bfrag = (bf16x8){lz, lx, ly, lz, BF16_ONE, BF16_ONE,
                                  hi16(q2), hi16(residual(q2))};
        }

        float run = 3.4e38f;

        for (int w = 0; w < N_ / CWIN; ++w) {
            __syncthreads();  // previous window's alds reads done
            {
                const uint4* pkw = pkc + w * 1024;
                #pragma unroll
                for (int c = 0; c < 4; ++c) {
                    const int i = c * 256 + (int)threadIdx.x;
                    alds[i] = pkw[i];
                }
            }
            __syncthreads();

            #pragma unroll
            for (int tile = 0; tile < CWIN / 32; ++tile) {
                union { uint4 u; bf16x8 v; } cv;
                cv.u = alds[kg * 512 + tile * 32 + col];
                f32x16 d = __builtin_amdgcn_mfma_f32_32x32x16_bf16(cv.v, bfrag, zero16, 0, 0, 0);
                float m0 = fminf(fminf(d[0],  d[1]),  fminf(d[2],  d[3]));
                float m1 = fminf(fminf(d[4],  d[5]),  fminf(d[6],  d[7]));
                float m2 = fminf(fminf(d[8],  d[9]),  fminf(d[10], d[11]));
                float m3 = fminf(fminf(d[12], d[13]), fminf(d[14], d[15]));
                run = fminf(run, fminf(fminf(m0, m1), fminf(m2, m3)));
            }
        }

        // lane and lane+32 hold disjoint candidate rows of the same query col.
        run = fminf(run, __shfl_xor(run, 32, 64));
        float contrib = (lane < 32) ? run * (0.5f / B_) : 0.f;  // q2 inside MFMA

        // pd + sp + tran folded here (768 blocks x 256 thr >= all elem counts).
        {
            const int PD_N = T_ * B_ * N_ * 3;
            const int SP_N = T_ * B_ * N_;
            const int gid = cid * 256 + (int)threadIdx.x;  // 0..196607
            if (gid < PD_N) {
                float d2 = drp[gid] - dp_all[gid];
                contrib = fmaf(d2 * (1.0f / B_), d2, contrib);
            }
            if (gid < SP_N) contrib += fabsf(pw[gid]) * (1.0f / (B_ * N_));
            if (gid < T_ * B_ * 3) {
                int tt = gid / (B_ * 3);
                int b2 = (gid / 3) % B_;
                int rr = gid % 3;
                float v = rm[tt * B_ * 16 + b2 * 16 + rr * 4 + 3];
                contrib = fmaf(v * (1.0f / B_), v, contrib);
            }
        }
        __syncthreads();
        float ssum = block_reduce<4>(contrib, (float*)smem4);
        if (threadIdx.x == 0) atomicAdd(out, ssum);
    }
}

// ---------------------------------------------------------------------------
extern "C" void kernel_launch(void* const* d_in, const int* in_sizes, int n_in,
                              void* d_out, int out_size, void* d_ws, size_t ws_size,
                              hipStream_t stream) {
    const float* pw  = (const float*)d_in[1];
    const float* drp = (const float*)d_in[2];
    const float* dp  = (const float*)d_in[3];
    const float* rm  = (const float*)d_in[4];
    const float* sp  = (const float*)d_in[5];
    const float* tp  = (const float*)d_in[6];
    float* out = (float*)d_out;
    uint4* ws = (uint4*)d_ws;  // needs 2.62 MB

    hipMemsetAsync(out, 0, sizeof(float), stream);
    prep_kernel<<<(20 * N_) / 256, 256, 0, stream>>>(sp, dp, tp, ws);
    mega_kernel<<<GROUPS * GRP_SZ, 256, 0, stream>>>(sp, dp, tp, drp, pw, rm, ws, out);
}

// Round 9
// 116.056 us; speedup vs baseline: 6.1004x; 1.0386x over previous
//
#include <hip/hip_runtime.h>

#define T_ 3
#define B_ 4
#define N_ 4096
#define K_ 8

// Uniform 7-resident grid: 256 groups of 7 = {4 KNN, 3 chamfer}.
// LDS 22528 B x 7 = 157.7 KiB <= 160 KiB -> all 7 co-resident on every CU;
// grid == residency (1792 = 7*256), so every CU gets identical work, no tail.
#define GRP_SZ  7
#define GRP_KNN 4
#define GROUPS  256
#define CWIN 512    // candidate window (16 KiB A-frags + 6 KiB raw coords)

typedef short bf16x8 __attribute__((ext_vector_type(8)));
typedef float f32x4  __attribute__((ext_vector_type(4)));
typedef float f32x16 __attribute__((ext_vector_type(16)));

// ---------------------------------------------------------------------------
template <int NW>
__device__ inline float block_reduce(float v, float* scratch) {
    #pragma unroll
    for (int off = 32; off > 0; off >>= 1) v += __shfl_down(v, off, 64);
    const int lane = threadIdx.x & 63, wid = threadIdx.x >> 6;
    if (lane == 0) scratch[wid] = v;
    __syncthreads();
    float s = 0.f;
    if (threadIdx.x == 0) {
        #pragma unroll
        for (int w = 0; w < NW; ++w) s += scratch[w];
    }
    return s;  // valid on thread 0 only
}

// Batcher odd-even 8-sort (19 CEs) — independent of running list (ILP).
#define CE_(A, i, j) { unsigned lo_ = min(A[i], A[j]); A[j] = max(A[i], A[j]); A[i] = lo_; }
__device__ inline void sort8(unsigned s[8]) {
    CE_(s,0,1) CE_(s,2,3) CE_(s,4,5) CE_(s,6,7)
    CE_(s,0,2) CE_(s,1,3) CE_(s,4,6) CE_(s,5,7)
    CE_(s,1,2) CE_(s,5,6)
    CE_(s,0,4) CE_(s,1,5) CE_(s,2,6) CE_(s,3,7)
    CE_(s,2,4) CE_(s,3,5)
    CE_(s,1,2) CE_(s,3,4) CE_(s,5,6)
}
// a (asc) := lowest-8 of union(a asc, s asc), sorted. Half-clean + bitonic merge.
__device__ inline void merge_top8(unsigned a[8], const unsigned s[8]) {
    #pragma unroll
    for (int i = 0; i < 8; ++i) a[i] = min(a[i], s[7 - i]);  // bitonic, lowest 8
    CE_(a,0,4) CE_(a,1,5) CE_(a,2,6) CE_(a,3,7)
    CE_(a,0,2) CE_(a,1,3) CE_(a,4,6) CE_(a,5,7)
    CE_(a,0,1) CE_(a,2,3) CE_(a,4,5) CE_(a,6,7)
}

// bf16 hi/lo split helpers (truncation; residual captures 8 more mantissa bits)
__device__ inline short hi16(float v) { return (short)(__float_as_uint(v) >> 16); }
__device__ inline float residual(float v) {
    return v - __uint_as_float(__float_as_uint(v) & 0xFFFF0000u);
}
__device__ inline unsigned pk2(short a, short b) {
    return (unsigned)(unsigned short)a | ((unsigned)(unsigned short)b << 16);
}
#define BF16_ONE ((short)0x3F80)

// Async global->LDS dword copy: no VGPR round-trip, vmcnt-counted; the
// compiler's vmcnt(0) drain at the next s_barrier is the synchronization.
// LDS dest is wave-uniform base + lane*4 (m104); global src is per-lane.
__device__ inline void async_ld(const float* g, float* l) {
    __builtin_amdgcn_global_load_lds(
        (const __attribute__((address_space(1))) void*)g,
        (__attribute__((address_space(3))) void*)l,
        4, 0, 0);
}

// ---------------------------------------------------------------------------
__global__ __launch_bounds__(256, 7) void mega_kernel(const float* __restrict__ src,
                                                      const float* __restrict__ dp_all,
                                                      const float* __restrict__ tp,
                                                      const float* __restrict__ drp,
                                                      const float* __restrict__ pw,
                                                      const float* __restrict__ rm,
                                                      float* __restrict__ out) {
    __shared__ uint4 smem4[1024];       // 16 KiB frag buffer, shared by all roles
    __shared__ float raw[CWIN * 3];     // 6 KiB raw xyz for the NEXT window
    const f32x4 zero4 = {0.f, 0.f, 0.f, 0.f};

    const int g = blockIdx.x / GRP_SZ;
    const int r = blockIdx.x % GRP_SZ;
    // Window-order stagger: co-resident blocks (g spaced by ~37) get spread
    // phases -> one block's staging hides under six others' compute.
    // Selection/min are window-order-independent, so result is exact.
    const int ph = g & 7;

    if (r < GRP_KNN) {  // ================= KNN + ARAP role (verified body)
        const int knn_id = g * GRP_KNN + r;  // 0..1023
        uint4* alds = smem4;  // A-frags: [tile(32)][quad(2)][m(16)] uint4
        const int b   = knn_id / (N_ / 16);
        const int qt0 = (knn_id % (N_ / 16)) * 16;  // 16 queries/block
        const float* sb = src + (size_t)b * N_ * 3;

        const int wid  = __builtin_amdgcn_readfirstlane(threadIdx.x >> 6);
        const int lane = threadIdx.x & 63;
        const int n    = lane & 15;   // query col (and A-row m for staging reads)
        const int quad = lane >> 4;
        const int rbase = quad * 4;   // D-row base (candidate offset in tile)
        const int qid  = qt0 + n;

        // B-frag: this lane's query, hi/lo split; |q|^2 injected at k14/k15.
        bf16x8 bfrag = (bf16x8)(short)0;
        {
            float x = sb[3 * qid], y = sb[3 * qid + 1], z = sb[3 * qid + 2];
            float q2 = fmaf(x, x, fmaf(y, y, z * z));
            short hx = hi16(x), hy = hi16(y), hz = hi16(z);
            short lx = hi16(residual(x)), ly = hi16(residual(y)), lz = hi16(residual(z));
            if (quad == 0) bfrag = (bf16x8){hx, hy, hz, hx, hy, hz, BF16_ONE, BF16_ONE};
            else if (quad == 1) bfrag = (bf16x8){lx, ly, lz, lx, ly, lz,
                                                 hi16(q2), hi16(residual(q2))};
        }

        unsigned a[K_];
        #pragma unroll
        for (int p = 0; p < K_; ++p) a[p] = 0xFFFFFFFFu;

        // Async-fill raw coords for the first (staggered) window.
        {
            const float* nb = sb + ph * (CWIN * 3);
            #pragma unroll
            for (int c = 0; c < 6; ++c) {
                const int chunk = c * 4 + wid;
                async_ld(nb + chunk * 64 + lane, raw + chunk * 64);
            }
        }

        for (int w = 0; w < N_ / CWIN; ++w) {  // 8 windows of 512 candidates
            const int wa = (w + ph) & 7;       // actual window this iteration
            __syncthreads();  // vmcnt(0) drain: raw[] holds window wa coords
            // Stage A-frags from raw LDS (stride-3 reads: 2-way aliasing, free).
            #pragma unroll
            for (int rr = 0; rr < 2; ++rr) {
                int jloc = rr * 256 + threadIdx.x;
                float x = raw[3 * jloc], y = raw[3 * jloc + 1], z = raw[3 * jloc + 2];
                float p2 = fmaf(x, x, fmaf(y, y, z * z));
                float mx = -2.f * x, my = -2.f * y, mz = -2.f * z;
                short mhx = hi16(mx), mhy = hi16(my), mhz = hi16(mz);
                short mlx = hi16(residual(mx)), mly = hi16(residual(my)), mlz = hi16(residual(mz));
                uint4 f0 = make_uint4(pk2(mhx, mhy), pk2(mhz, mlx), pk2(mly, mlz),
                                      pk2(hi16(p2), hi16(residual(p2))));
                uint4 f1 = make_uint4(f0.x, f0.y, f0.z, pk2(BF16_ONE, BF16_ONE));
                int tile = jloc >> 4, m = jloc & 15;
                alds[tile * 32 + m]      = f0;  // k0-7 slice
                alds[tile * 32 + 16 + m] = f1;  // k8-15 slice
            }
            __syncthreads();

            // Issue next window's raw copies; latency hides under the whole
            // compute phase, drained by next iteration's first barrier.
            if (w + 1 < N_ / CWIN) {
                const int wn = (w + 1 + ph) & 7;
                const float* nb = sb + wn * (CWIN * 3);
                #pragma unroll
                for (int c = 0; c < 6; ++c) {
                    const int chunk = c * 4 + wid;
                    async_ld(nb + chunk * 64 + lane, raw + chunk * 64);
                }
            }

            // This wave's quarter: tiles wid*8 .. wid*8+7 (batches of 2 tiles).
            #pragma unroll
            for (int bt = 0; bt < 4; ++bt) {
                unsigned s8[8];
                #pragma unroll
                for (int h = 0; h < 2; ++h) {
                    const int tile = wid * 8 + bt * 2 + h;
                    const int tbg  = wa * CWIN + tile * 16;  // 16-aligned
                    bf16x8 af = (bf16x8)(short)0;
                    if (quad < 2) {
                        union { uint4 u; bf16x8 v; } cv;
                        cv.u = alds[tile * 32 + quad * 16 + n];
                        af = cv.v;
                    }
                    f32x4 d = __builtin_amdgcn_mfma_f32_16x16x32_bf16(af, bfrag, zero4, 0, 0, 0);
                    #pragma unroll
                    for (int rr = 0; rr < 4; ++rr)  // idx bits (0-11) disjoint from tbg
                        s8[h * 4 + rr] = (__float_as_uint(d[rr]) & 0xFFFFF000u)
                                         | (unsigned)(tbg | (rbase + rr));
                    if (tbg == qt0) {  // wave-uniform: the one self-overlap tile
                        #pragma unroll
                        for (int rr = 0; rr < 4; ++rr)
                            if (rbase + rr == n) s8[h * 4 + rr] = 0xFFFFFFFFu;
                    }
                }
                sort8(s8);
                merge_top8(a, s8);
            }
        }

        // Fold the 4 row-quads of each query column (lanes n, n+16, n+32, n+48).
        #pragma unroll
        for (int mk = 16; mk <= 32; mk <<= 1) {
            unsigned t[8];
            #pragma unroll
            for (int e = 0; e < K_; ++e) t[e] = __shfl_xor(a[e], mk, 64);
            merge_top8(a, t);
        }

        // Cross-wave merge (4 partial lists per query) + publish indices.
        __syncthreads();  // A-frag reads done; reuse LDS
        unsigned* sm = (unsigned*)smem4;          // [wave*16+q]*9+e  (<576)
        unsigned* nidx = (unsigned*)smem4 + 1024; // 128 entries
        if (lane < 16) {
            #pragma unroll
            for (int e = 0; e < K_; ++e) sm[(wid * 16 + n) * 9 + e] = a[e];
        }
        __syncthreads();
        if (threadIdx.x < 16) {
            const int q = threadIdx.x;
            unsigned md[K_];
            #pragma unroll
            for (int e = 0; e < K_; ++e) md[e] = sm[q * 9 + e];
            #pragma unroll
            for (int wv = 1; wv < 4; ++wv) {
                unsigned t[8];
                #pragma unroll
                for (int e = 0; e < K_; ++e) t[e] = sm[(wv * 16 + q) * 9 + e];
                merge_top8(md, t);
            }
            #pragma unroll
            for (int e = 0; e < K_; ++e) nidx[q * 8 + e] = md[e] & 0xFFFu;
        }
        __syncthreads();

        // Fused ARAP: 128 threads = 16 queries x 8 neighbors, all 3 t stages.
        float acc = 0.f;
        if (threadIdx.x < 16 * K_) {
            const int q  = threadIdx.x >> 3;
            const int qi = qt0 + q;
            const int j  = (int)nidx[threadIdx.x];
            float sx = sb[3 * qi], sy = sb[3 * qi + 1], sz = sb[3 * qi + 2];
            float ex = sb[3 * j] - sx, ey = sb[3 * j + 1] - sy, ez = sb[3 * j + 2] - sz;
            float sd = sqrtf(fmaf(ex, ex, fmaf(ey, ey, ez * ez)) + 1e-5f);
            #pragma unroll
            for (int t = 0; t < T_; ++t) {
                const float* dpb = dp_all + ((size_t)(t * B_ + b)) * N_ * 3;
                float dx = dpb[3 * j] - dpb[3 * qi];
                float dy = dpb[3 * j + 1] - dpb[3 * qi + 1];
                float dz = dpb[3 * j + 2] - dpb[3 * qi + 2];
                float dd = sqrtf(fmaf(dx, dx, fmaf(dy, dy, dz * dz)) + 1e-5f);
                float df = dd - sd;
                acc = fmaf(df, df, acc);
            }
        }
        float s = block_reduce<4>(acc, (float*)smem4);
        if (threadIdx.x == 0) atomicAdd(out, s * (1.0f / B_));

    } else {  // ====== chamfer role — 32x32x16 (verified body, 128 q/block)
        const f32x16 zero16 = {0.f,0.f,0.f,0.f, 0.f,0.f,0.f,0.f,
                               0.f,0.f,0.f,0.f, 0.f,0.f,0.f,0.f};
        uint4* alds = smem4;  // [kg(2)][512 cands] uint4
        const int cid   = g * 3 + (r - GRP_KNN);  // 0..767
        const int combo = cid >> 5;   // ((t*B+b)*2+dir), 0..23
        const int slab  = cid & 31;   // 128-query slab
        const int dir = combo & 1;
        const int tb  = combo >> 1;
        const int b = tb % B_, t = tb / B_;

        const float* dpb = dp_all + ((size_t)(t * B_ + b)) * N_ * 3;
        const float* tpb = tp + (size_t)b * N_ * 3;
        const float* cbase = dir ? dpb : tpb;  // candidates
        const float* qbase = dir ? tpb : dpb;  // queries

        const int lane = threadIdx.x & 63;
        const int wid  = __builtin_amdgcn_readfirstlane(threadIdx.x >> 6);
        const int col  = lane & 31;   // query column (B) / A-row within tile
        const int kg   = lane >> 5;   // k-octet (0: k0-7, 1: k8-15)

        bf16x8 bfrag;
        {
            const int qid = slab * 128 + wid * 32 + col;
            float x = qbase[3 * qid], y = qbase[3 * qid + 1], z = qbase[3 * qid + 2];
            float q2 = fmaf(x, x, fmaf(y, y, z * z));
            short hx = hi16(x), hy = hi16(y), hz = hi16(z);
            short lx = hi16(residual(x)), ly = hi16(residual(y)), lz = hi16(residual(z));
            if (kg == 0) bfrag = (bf16x8){hx, hy, hz, hx, hy, hz, lx, ly};
            else bfrag = (bf16x8){lz, lx, ly, lz, BF16_ONE, BF16_ONE,
                                  hi16(q2), hi16(residual(q2))};
        }

        float run = 3.4e38f;

        // Async-fill raw coords for the first (staggered) window.
        {
            const float* nb = cbase + ph * (CWIN * 3);
            #pragma unroll
            for (int c = 0; c < 6; ++c) {
                const int chunk = c * 4 + wid;
                async_ld(nb + chunk * 64 + lane, raw + chunk * 64);
            }
        }

        for (int w = 0; w < N_ / CWIN; ++w) {
            __syncthreads();  // vmcnt(0) drain: raw[] holds this window's coords
            #pragma unroll
            for (int rr = 0; rr < 2; ++rr) {
                int j = rr * 256 + (int)threadIdx.x;  // consecutive -> conflict-free
                float x = raw[3 * j], y = raw[3 * j + 1], z = raw[3 * j + 2];
                float p2 = fmaf(x, x, fmaf(y, y, z * z));
                float mx = -2.f * x, my = -2.f * y, mz = -2.f * z;
                short mhx = hi16(mx), mhy = hi16(my), mhz = hi16(mz);
                short mlx = hi16(residual(mx)), mly = hi16(residual(my)), mlz = hi16(residual(mz));
                unsigned w0 = pk2(mhx, mhy), w1 = pk2(mhz, mlx), w2 = pk2(mly, mlz);
                unsigned pw2 = pk2(hi16(p2), hi16(residual(p2)));
                alds[j]       = make_uint4(w0, w1, w2, w0);                        // k0-7
                alds[512 + j] = make_uint4(w1, w2, pw2, pk2(BF16_ONE, BF16_ONE)); // k8-15
            }
            __syncthreads();

            // Issue next window's raw copies (hide under the 16-tile compute).
            if (w + 1 < N_ / CWIN) {
                const int wn = (w + 1 + ph) & 7;
                const float* nb = cbase + wn * (CWIN * 3);
                #pragma unroll
                for (int c = 0; c < 6; ++c) {
                    const int chunk = c * 4 + wid;
                    async_ld(nb + chunk * 64 + lane, raw + chunk * 64);
                }
            }

            #pragma unroll
            for (int tile = 0; tile < CWIN / 32; ++tile) {
                union { uint4 u; bf16x8 v; } cv;
                cv.u = alds[kg * 512 + tile * 32 + col];
                f32x16 d = __builtin_amdgcn_mfma_f32_32x32x16_bf16(cv.v, bfrag, zero16, 0, 0, 0);
                float m0 = fminf(fminf(d[0],  d[1]),  fminf(d[2],  d[3]));
                float m1 = fminf(fminf(d[4],  d[5]),  fminf(d[6],  d[7]));
                float m2 = fminf(fminf(d[8],  d[9]),  fminf(d[10], d[11]));
                float m3 = fminf(fminf(d[12], d[13]), fminf(d[14], d[15]));
                run = fminf(run, fminf(fminf(m0, m1), fminf(m2, m3)));
            }
        }

        // lane and lane+32 hold disjoint candidate rows of the same query col.
        run = fminf(run, __shfl_xor(run, 32, 64));
        float contrib = (lane < 32) ? run * (0.5f / B_) : 0.f;  // q2 inside MFMA

        // pd + sp + tran folded here (768 blocks x 256 thr >= all elem counts:
        // PD_N=147456, SP_N=49152, tran=36 — single-shot conditionals).
        {
            const int PD_N = T_ * B_ * N_ * 3;
            const int SP_N = T_ * B_ * N_;
            const int gid = cid * 256 + (int)threadIdx.x;  // 0..196607
            if (gid < PD_N) {
                float d2 = drp[gid] - dp_all[gid];
                contrib = fmaf(d2 * (1.0f / B_), d2, contrib);
            }
            if (gid < SP_N) contrib += fabsf(pw[gid]) * (1.0f / (B_ * N_));
            if (gid < T_ * B_ * 3) {
                int tt = gid / (B_ * 3);
                int b2 = (gid / 3) % B_;
                int rr = gid % 3;
                float v = rm[tt * B_ * 16 + b2 * 16 + rr * 4 + 3];
                contrib = fmaf(v * (1.0f / B_), v, contrib);
            }
        }
        __syncthreads();
        float ssum = block_reduce<4>(contrib, (float*)smem4);
        if (threadIdx.x == 0) atomicAdd(out, ssum);
    }
}

// ---------------------------------------------------------------------------
extern "C" void kernel_launch(void* const* d_in, const int* in_sizes, int n_in,
                              void* d_out, int out_size, void* d_ws, size_t ws_size,
                              hipStream_t stream) {
    const float* pw  = (const float*)d_in[1];
    const float* drp = (const float*)d_in[2];
    const float* dp  = (const float*)d_in[3];
    const float* rm  = (const float*)d_in[4];
    const float* sp  = (const float*)d_in[5];
    const float* tp  = (const float*)d_in[6];
    float* out = (float*)d_out;

    hipMemsetAsync(out, 0, sizeof(float), stream);
    mega_kernel<<<GROUPS * GRP_SZ, 256, 0, stream>>>(sp, dp, tp, drp, pw, rm, out);
}

// Round 10
// 115.265 us; speedup vs baseline: 6.1423x; 1.0069x over previous
//
#include <hip/hip_runtime.h>

#define T_ 3
#define B_ 4
#define N_ 4096
#define K_ 8

// Uniform 7-resident grid: 256 groups of 7 = {4 KNN, 3 chamfer}.
// LDS 22528 B x 7 = 157.7 KiB <= 160 KiB -> all 7 co-resident on every CU.
#define GRP_SZ  7
#define GRP_KNN 4
#define GROUPS  256
#define CWIN 512    // candidate window (16 KiB A-frags + 6 KiB raw coords)

typedef short bf16x8 __attribute__((ext_vector_type(8)));
typedef float f32x4  __attribute__((ext_vector_type(4)));
typedef float f32x16 __attribute__((ext_vector_type(16)));

// ---------------------------------------------------------------------------
template <int NW>
__device__ inline float block_reduce(float v, float* scratch) {
    #pragma unroll
    for (int off = 32; off > 0; off >>= 1) v += __shfl_down(v, off, 64);
    const int lane = threadIdx.x & 63, wid = threadIdx.x >> 6;
    if (lane == 0) scratch[wid] = v;
    __syncthreads();
    float s = 0.f;
    if (threadIdx.x == 0) {
        #pragma unroll
        for (int w = 0; w < NW; ++w) s += scratch[w];
    }
    return s;  // valid on thread 0 only
}

// Batcher odd-even 8-sort (19 CEs) — independent of running list (ILP).
#define CE_(A, i, j) { unsigned lo_ = min(A[i], A[j]); A[j] = max(A[i], A[j]); A[i] = lo_; }
__device__ inline void sort8(unsigned s[8]) {
    CE_(s,0,1) CE_(s,2,3) CE_(s,4,5) CE_(s,6,7)
    CE_(s,0,2) CE_(s,1,3) CE_(s,4,6) CE_(s,5,7)
    CE_(s,1,2) CE_(s,5,6)
    CE_(s,0,4) CE_(s,1,5) CE_(s,2,6) CE_(s,3,7)
    CE_(s,2,4) CE_(s,3,5)
    CE_(s,1,2) CE_(s,3,4) CE_(s,5,6)
}
// a (asc) := lowest-8 of union(a asc, s asc), sorted. Half-clean + bitonic merge.
__device__ inline void merge_top8(unsigned a[8], const unsigned s[8]) {
    #pragma unroll
    for (int i = 0; i < 8; ++i) a[i] = min(a[i], s[7 - i]);  // bitonic, lowest 8
    CE_(a,0,4) CE_(a,1,5) CE_(a,2,6) CE_(a,3,7)
    CE_(a,0,2) CE_(a,1,3) CE_(a,4,6) CE_(a,5,7)
    CE_(a,0,1) CE_(a,2,3) CE_(a,4,5) CE_(a,6,7)
}

// bf16 hi/lo split helpers (truncation; residual captures 8 more mantissa bits)
__device__ inline short hi16(float v) { return (short)(__float_as_uint(v) >> 16); }
__device__ inline float residual(float v) {
    return v - __uint_as_float(__float_as_uint(v) & 0xFFFF0000u);
}
__device__ inline unsigned pk2(short a, short b) {
    return (unsigned)(unsigned short)a | ((unsigned)(unsigned short)b << 16);
}
#define BF16_ONE ((short)0x3F80)

// Async global->LDS dword copy: no VGPR round-trip, vmcnt-counted.
// LDS dest is wave-uniform base + lane*4 (m104); global src is per-lane.
__device__ inline void async_ld(const float* g, float* l) {
    __builtin_amdgcn_global_load_lds(
        (const __attribute__((address_space(1))) void*)g,
        (__attribute__((address_space(3))) void*)l,
        4, 0, 0);
}

// Wave-level wait for this wave's outstanding async_ld ops (no block barrier).
// "memory" clobber orders the subsequent LDS reads; sched_barrier pins it.
__device__ inline void wave_wait_vm0() {
    asm volatile("s_waitcnt vmcnt(0)" ::: "memory");
    __builtin_amdgcn_sched_barrier(0);
}

// ---------------------------------------------------------------------------
__global__ __launch_bounds__(256, 7) void mega_kernel(const float* __restrict__ src,
                                                      const float* __restrict__ dp_all,
                                                      const float* __restrict__ tp,
                                                      const float* __restrict__ drp,
                                                      const float* __restrict__ pw,
                                                      const float* __restrict__ rm,
                                                      float* __restrict__ out) {
    __shared__ uint4 smem4[1024];       // 16 KiB frag buffer, shared by all roles
    __shared__ float raw[CWIN * 3];     // 6 KiB raw xyz for the NEXT window
    const f32x4 zero4 = {0.f, 0.f, 0.f, 0.f};

    const int g = blockIdx.x / GRP_SZ;
    const int r = blockIdx.x % GRP_SZ;
    // Window-order stagger (r9-verified): decorrelates block phases; also
    // keeps L2 read spread. Selection/min are window-order-independent.
    const int ph = g & 7;

    if (r < GRP_KNN) {  // ========== KNN + ARAP role — BARRIER-FREE main loop
        // Dataflow is wave-local end-to-end: wave wid computes tiles
        // wid*8..wid*8+7 = candidates [wid*128,+128) = raw floats
        // [wid*384,+384) = async chunks wid*6..wid*6+5. Staging restriped
        // wave-locally -> no inter-wave alds/raw dependency -> the 4 waves
        // free-run with per-wave vmcnt waits; stalls of one wave hide under
        // the others' compute (intra-block stagger, zero barrier cost).
        const int knn_id = g * GRP_KNN + r;  // 0..1023
        uint4* alds = smem4;  // A-frags: [tile(32)][quad(2)][m(16)] uint4
        const int b   = knn_id / (N_ / 16);
        const int qt0 = (knn_id % (N_ / 16)) * 16;  // 16 queries/block
        const float* sb = src + (size_t)b * N_ * 3;

        const int wid  = __builtin_amdgcn_readfirstlane(threadIdx.x >> 6);
        const int lane = threadIdx.x & 63;
        const int n    = lane & 15;   // query col
        const int quad = lane >> 4;
        const int rbase = quad * 4;   // D-row base (candidate offset in tile)
        const int qid  = qt0 + n;

        // B-frag: this lane's query, hi/lo split; |q|^2 injected at k14/k15.
        bf16x8 bfrag = (bf16x8)(short)0;
        {
            float x = sb[3 * qid], y = sb[3 * qid + 1], z = sb[3 * qid + 2];
            float q2 = fmaf(x, x, fmaf(y, y, z * z));
            short hx = hi16(x), hy = hi16(y), hz = hi16(z);
            short lx = hi16(residual(x)), ly = hi16(residual(y)), lz = hi16(residual(z));
            if (quad == 0) bfrag = (bf16x8){hx, hy, hz, hx, hy, hz, BF16_ONE, BF16_ONE};
            else if (quad == 1) bfrag = (bf16x8){lx, ly, lz, lx, ly, lz,
                                                 hi16(q2), hi16(residual(q2))};
        }

        unsigned a[K_];
        #pragma unroll
        for (int p = 0; p < K_; ++p) a[p] = 0xFFFFFFFFu;

        // Async-fill THIS WAVE's raw chunks for the first (staggered) window.
        {
            const float* nb = sb + ph * (CWIN * 3);
            #pragma unroll
            for (int c = 0; c < 6; ++c) {
                const int chunk = wid * 6 + c;  // wave-local: floats [wid*384,+384)
                async_ld(nb + chunk * 64 + lane, raw + chunk * 64);
            }
        }

        for (int w = 0; w < N_ / CWIN; ++w) {  // 8 windows of 512 candidates
            const int wa = (w + ph) & 7;       // actual window this iteration
            wave_wait_vm0();  // this wave's raw quarter is ready (no barrier)

            // Pack THIS WAVE's quarter: candidates [wid*128, wid*128+128).
            #pragma unroll
            for (int rr = 0; rr < 2; ++rr) {
                int jloc = wid * 128 + rr * 64 + lane;
                float x = raw[3 * jloc], y = raw[3 * jloc + 1], z = raw[3 * jloc + 2];
                float p2 = fmaf(x, x, fmaf(y, y, z * z));
                float mx = -2.f * x, my = -2.f * y, mz = -2.f * z;
                short mhx = hi16(mx), mhy = hi16(my), mhz = hi16(mz);
                short mlx = hi16(residual(mx)), mly = hi16(residual(my)), mlz = hi16(residual(mz));
                uint4 f0 = make_uint4(pk2(mhx, mhy), pk2(mhz, mlx), pk2(mly, mlz),
                                      pk2(hi16(p2), hi16(residual(p2))));
                uint4 f1 = make_uint4(f0.x, f0.y, f0.z, pk2(BF16_ONE, BF16_ONE));
                int tile = jloc >> 4, m = jloc & 15;
                alds[tile * 32 + m]      = f0;  // k0-7 slice
                alds[tile * 32 + 16 + m] = f1;  // k8-15 slice
            }

            // Issue next window's raw copies for this wave (raw now free);
            // latency hides under this window's compute.
            if (w + 1 < N_ / CWIN) {
                const int wn = (w + 1 + ph) & 7;
                const float* nb = sb + wn * (CWIN * 3);
                #pragma unroll
                for (int c = 0; c < 6; ++c) {
                    const int chunk = wid * 6 + c;
                    async_ld(nb + chunk * 64 + lane, raw + chunk * 64);
                }
            }

            // Compute this wave's own tiles (the ones it just packed).
            #pragma unroll
            for (int bt = 0; bt < 4; ++bt) {
                unsigned s8[8];
                #pragma unroll
                for (int h = 0; h < 2; ++h) {
                    const int tile = wid * 8 + bt * 2 + h;
                    const int tbg  = wa * CWIN + tile * 16;  // 16-aligned
                    bf16x8 af = (bf16x8)(short)0;
                    if (quad < 2) {
                        union { uint4 u; bf16x8 v; } cv;
                        cv.u = alds[tile * 32 + quad * 16 + n];
                        af = cv.v;
                    }
                    f32x4 d = __builtin_amdgcn_mfma_f32_16x16x32_bf16(af, bfrag, zero4, 0, 0, 0);
                    #pragma unroll
                    for (int rr = 0; rr < 4; ++rr)  // idx bits (0-11) disjoint from tbg
                        s8[h * 4 + rr] = (__float_as_uint(d[rr]) & 0xFFFFF000u)
                                         | (unsigned)(tbg | (rbase + rr));
                    if (tbg == qt0) {  // wave-uniform: the one self-overlap tile
                        #pragma unroll
                        for (int rr = 0; rr < 4; ++rr)
                            if (rbase + rr == n) s8[h * 4 + rr] = 0xFFFFFFFFu;
                    }
                }
                sort8(s8);
                merge_top8(a, s8);
            }
        }

        // Fold the 4 row-quads of each query column (lanes n, n+16, n+32, n+48).
        #pragma unroll
        for (int mk = 16; mk <= 32; mk <<= 1) {
            unsigned t[8];
            #pragma unroll
            for (int e = 0; e < K_; ++e) t[e] = __shfl_xor(a[e], mk, 64);
            merge_top8(a, t);
        }

        // Cross-wave merge (4 partial lists per query) + publish indices.
        __syncthreads();  // all waves done with their alds quarters; reuse LDS
        unsigned* sm = (unsigned*)smem4;          // [wave*16+q]*9+e  (<576)
        unsigned* nidx = (unsigned*)smem4 + 1024; // 128 entries
        if (lane < 16) {
            #pragma unroll
            for (int e = 0; e < K_; ++e) sm[(wid * 16 + n) * 9 + e] = a[e];
        }
        __syncthreads();
        if (threadIdx.x < 16) {
            const int q = threadIdx.x;
            unsigned md[K_];
            #pragma unroll
            for (int e = 0; e < K_; ++e) md[e] = sm[q * 9 + e];
            #pragma unroll
            for (int wv = 1; wv < 4; ++wv) {
                unsigned t[8];
                #pragma unroll
                for (int e = 0; e < K_; ++e) t[e] = sm[(wv * 16 + q) * 9 + e];
                merge_top8(md, t);
            }
            #pragma unroll
            for (int e = 0; e < K_; ++e) nidx[q * 8 + e] = md[e] & 0xFFFu;
        }
        __syncthreads();

        // Fused ARAP: 128 threads = 16 queries x 8 neighbors, all 3 t stages.
        float acc = 0.f;
        if (threadIdx.x < 16 * K_) {
            const int q  = threadIdx.x >> 3;
            const int qi = qt0 + q;
            const int j  = (int)nidx[threadIdx.x];
            float sx = sb[3 * qi], sy = sb[3 * qi + 1], sz = sb[3 * qi + 2];
            float ex = sb[3 * j] - sx, ey = sb[3 * j + 1] - sy, ez = sb[3 * j + 2] - sz;
            float sd = sqrtf(fmaf(ex, ex, fmaf(ey, ey, ez * ez)) + 1e-5f);
            #pragma unroll
            for (int t = 0; t < T_; ++t) {
                const float* dpb = dp_all + ((size_t)(t * B_ + b)) * N_ * 3;
                float dx = dpb[3 * j] - dpb[3 * qi];
                float dy = dpb[3 * j + 1] - dpb[3 * qi + 1];
                float dz = dpb[3 * j + 2] - dpb[3 * qi + 2];
                float dd = sqrtf(fmaf(dx, dx, fmaf(dy, dy, dz * dz)) + 1e-5f);
                float df = dd - sd;
                acc = fmaf(df, df, acc);
            }
        }
        float s = block_reduce<4>(acc, (float*)smem4);
        if (threadIdx.x == 0) atomicAdd(out, s * (1.0f / B_));

    } else {  // ====== chamfer role — 32x32x16 (verified body, 128 q/block)
        const f32x16 zero16 = {0.f,0.f,0.f,0.f, 0.f,0.f,0.f,0.f,
                               0.f,0.f,0.f,0.f, 0.f,0.f,0.f,0.f};
        uint4* alds = smem4;  // [kg(2)][512 cands] uint4
        const int cid   = g * 3 + (r - GRP_KNN);  // 0..767
        const int combo = cid >> 5;   // ((t*B+b)*2+dir), 0..23
        const int slab  = cid & 31;   // 128-query slab
        const int dir = combo & 1;
        const int tb  = combo >> 1;
        const int b = tb % B_, t = tb / B_;

        const float* dpb = dp_all + ((size_t)(t * B_ + b)) * N_ * 3;
        const float* tpb = tp + (size_t)b * N_ * 3;
        const float* cbase = dir ? dpb : tpb;  // candidates
        const float* qbase = dir ? tpb : dpb;  // queries

        const int lane = threadIdx.x & 63;
        const int wid  = __builtin_amdgcn_readfirstlane(threadIdx.x >> 6);
        const int col  = lane & 31;   // query column (B) / A-row within tile
        const int kg   = lane >> 5;   // k-octet (0: k0-7, 1: k8-15)

        bf16x8 bfrag;
        {
            const int qid = slab * 128 + wid * 32 + col;
            float x = qbase[3 * qid], y = qbase[3 * qid + 1], z = qbase[3 * qid + 2];
            float q2 = fmaf(x, x, fmaf(y, y, z * z));
            short hx = hi16(x), hy = hi16(y), hz = hi16(z);
            short lx = hi16(residual(x)), ly = hi16(residual(y)), lz = hi16(residual(z));
            if (kg == 0) bfrag = (bf16x8){hx, hy, hz, hx, hy, hz, lx, ly};
            else bfrag = (bf16x8){lz, lx, ly, lz, BF16_ONE, BF16_ONE,
                                  hi16(q2), hi16(residual(q2))};
        }

        float run = 3.4e38f;

        // Async-fill raw coords for the first (staggered) window.
        {
            const float* nb = cbase + ph * (CWIN * 3);
            #pragma unroll
            for (int c = 0; c < 6; ++c) {
                const int chunk = c * 4 + wid;
                async_ld(nb + chunk * 64 + lane, raw + chunk * 64);
            }
        }

        for (int w = 0; w < N_ / CWIN; ++w) {
            __syncthreads();  // vmcnt(0) drain: raw[] holds this window's coords
            #pragma unroll
            for (int rr = 0; rr < 2; ++rr) {
                int j = rr * 256 + (int)threadIdx.x;  // consecutive -> conflict-free
                float x = raw[3 * j], y = raw[3 * j + 1], z = raw[3 * j + 2];
                float p2 = fmaf(x, x, fmaf(y, y, z * z));
                float mx = -2.f * x, my = -2.f * y, mz = -2.f * z;
                short mhx = hi16(mx), mhy = hi16(my), mhz = hi16(mz);
                short mlx = hi16(residual(mx)), mly = hi16(residual(my)), mlz = hi16(residual(mz));
                unsigned w0 = pk2(mhx, mhy), w1 = pk2(mhz, mlx), w2 = pk2(mly, mlz);
                unsigned pw2 = pk2(hi16(p2), hi16(residual(p2)));
                alds[j]       = make_uint4(w0, w1, w2, w0);                        // k0-7
                alds[512 + j] = make_uint4(w1, w2, pw2, pk2(BF16_ONE, BF16_ONE)); // k8-15
            }
            __syncthreads();

            // Issue next window's raw copies (hide under the 16-tile compute).
            if (w + 1 < N_ / CWIN) {
                const int wn = (w + 1 + ph) & 7;
                const float* nb = cbase + wn * (CWIN * 3);
                #pragma unroll
                for (int c = 0; c < 6; ++c) {
                    const int chunk = c * 4 + wid;
                    async_ld(nb + chunk * 64 + lane, raw + chunk * 64);
                }
            }

            #pragma unroll
            for (int tile = 0; tile < CWIN / 32; ++tile) {
                union { uint4 u; bf16x8 v; } cv;
                cv.u = alds[kg * 512 + tile * 32 + col];
                f32x16 d = __builtin_amdgcn_mfma_f32_32x32x16_bf16(cv.v, bfrag, zero16, 0, 0, 0);
                float m0 = fminf(fminf(d[0],  d[1]),  fminf(d[2],  d[3]));
                float m1 = fminf(fminf(d[4],  d[5]),  fminf(d[6],  d[7]));
                float m2 = fminf(fminf(d[8],  d[9]),  fminf(d[10], d[11]));
                float m3 = fminf(fminf(d[12], d[13]), fminf(d[14], d[15]));
                run = fminf(run, fminf(fminf(m0, m1), fminf(m2, m3)));
            }
        }

        // lane and lane+32 hold disjoint candidate rows of the same query col.
        run = fminf(run, __shfl_xor(run, 32, 64));
        float contrib = (lane < 32) ? run * (0.5f / B_) : 0.f;  // q2 inside MFMA

        // pd + sp + tran folded here (768 blocks x 256 thr >= all elem counts).
        {
            const int PD_N = T_ * B_ * N_ * 3;
            const int SP_N = T_ * B_ * N_;
            const int gid = cid * 256 + (int)threadIdx.x;  // 0..196607
            if (gid < PD_N) {
                float d2 = drp[gid] - dp_all[gid];
                contrib = fmaf(d2 * (1.0f / B_), d2, contrib);
            }
            if (gid < SP_N) contrib += fabsf(pw[gid]) * (1.0f / (B_ * N_));
            if (gid < T_ * B_ * 3) {
                int tt = gid / (B_ * 3);
                int b2 = (gid / 3) % B_;
                int rr = gid % 3;
                float v = rm[tt * B_ * 16 + b2 * 16 + rr * 4 + 3];
                contrib = fmaf(v * (1.0f / B_), v, contrib);
            }
        }
        __syncthreads();
        float ssum = block_reduce<4>(contrib, (float*)smem4);
        if (threadIdx.x == 0) atomicAdd(out, ssum);
    }
}

// ---------------------------------------------------------------------------
extern "C" void kernel_launch(void* const* d_in, const int* in_sizes, int n_in,
                              void* d_out, int out_size, void* d_ws, size_t ws_size,
                              hipStream_t stream) {
    const float* pw  = (const float*)d_in[1];
    const float* drp = (const float*)d_in[2];
    const float* dp  = (const float*)d_in[3];
    const float* rm  = (const float*)d_in[4];
    const float* sp  = (const float*)d_in[5];
    const float* tp  = (const float*)d_in[6];
    float* out = (float*)d_out;

    hipMemsetAsync(out, 0, sizeof(float), stream);
    mega_kernel<<<GROUPS * GRP_SZ, 256, 0, stream>>>(sp, dp, tp, drp, pw, rm, out);
}